// Round 12
// baseline (169.214 us; speedup 1.0000x reference)
//
#include <hip/hip_runtime.h>
#include <math.h>

#define NB 65536
#define IMGD 32
#define NPIX 1024
#define PSTRIDE 20

typedef float v2f __attribute__((ext_vector_type(2)));

// Packed FP32 (VOP3P, full-rate on CDNA3/4). Compiler never forms these from
// scalar f32 -> emit directly. 64-bit "v" operands = aligned VGPR pairs.
#define PK_FMA(d, a, b, c) \
    asm("v_pk_fma_f32 %0, %1, %2, %3" : "=v"(d) : "v"(a), "v"(b), "v"(c))
#define PK_FMA_CLAMP(d, a, b, c) \
    asm("v_pk_fma_f32 %0, %1, %2, %3 clamp" : "=v"(d) : "v"(a), "v"(b), "v"(c))
#define PK_FMA_ACC(acc, a, b) \
    asm("v_pk_fma_f32 %0, %1, %2, %0" : "+v"(acc) : "v"(a), "v"(b))
#define PK_ADD(d, a, b) \
    asm("v_pk_add_f32 %0, %1, %2" : "=v"(d) : "v"(a), "v"(b))
#define PK_ADD_ACC(acc, a) \
    asm("v_pk_add_f32 %0, %0, %1" : "+v"(acc) : "v"(a))
#define PK_MUL(d, a, b) \
    asm("v_pk_mul_f32 %0, %1, %2" : "=v"(d) : "v"(a), "v"(b))

// Constant tables (same for every image) and per-image derived params.
__device__ __align__(16) float g_r[NPIX];
__device__ __align__(16) float g_th[NPIX];   // theta * 5/(2*pi)
__device__ __align__(16) float g_par[(size_t)NB * PSTRIDE];

__global__ void init_params_kernel(const float* __restrict__ W) {
    int b = blockIdx.x * blockDim.x + threadIdx.x;

    // block 0 additionally fills the constant pixel tables (4 px/thread)
    if (blockIdx.x == 0) {
        int t = threadIdx.x;
        for (int k = 0; k < 4; ++k) {
            int p = t * 4 + k;
            int x = p >> 5, y = p & 31;
            float dx = (float)(x - 16), dy = (float)(y - 16);
            // exact integer squares; sqrtf correctly rounded -> bitwise match
            g_r[p] = sqrtf(dx * dx + dy * dy);
            // theta = atan2(yy-CY, xx-CX); fold 5/(2*pi) for revolution sin
            g_th[p] = atan2f(dy, dx) * 0.79577471545947668f;
        }
    }
    if (b >= NB) return;
    const float* w = W + (size_t)b * 16;
    float* P = g_par + (size_t)b * PSTRIDE;

    float w0 = w[0], w1 = w[1], w2 = w[2], w3 = w[3], w4 = w[4], w5 = w[5],
          w6 = w[6], w7 = w[7], w8 = w[8], w9 = w[9], w10 = w[10], w11 = w[11],
          w12 = w[12], w13 = w[13], w14 = w[14], w15 = w[15];

    P[0] = w0 * 5.0f;                                   // a0
    // layer 1: half = floor(clip(|w1|*8, 2, 12)); |w1|*8 exact (pow2 mul)
    float half = floorf(fminf(fmaxf(fabsf(w1) * 8.0f, 2.0f), 12.0f));
    P[1] = 16.0f - half;                                // lo (exact)
    P[2] = 16.0f + half;                                // hi (exact)
    P[3] = w2 * 0.15625f;                               // s2 (10/64 rev)
    P[4] = w3 * 0.15625f;                               // s3
    P[5] = w4 * 0.0390625f;                             // s4 (5/128 rev)
    P[6] = w5 * 0.15625f;                               // s5o
    P[7] = w6;                                          // bias
    // layer 7 blob center: trunc(16 + w7*5), mul/add un-fused to match ref
    float t7 = __fadd_rn(16.0f, __fmul_rn(w7, 5.0f));
    P[8] = truncf(t7);                                  // bxy
    float sg = 4.0f + fabsf(w7) * 4.0f;
    P[9] = -1.0f / (2.0f * sg * sg);                    // nk
    P[10] = w8 * 10.0f;                                 // t8 (single mul)
    // layer 9: cb = floor(clip(|w9|*8 + 2, 2, 16)); exact chain
    float cb = floorf(fminf(fmaxf(__fadd_rn(fabsf(w9) * 8.0f, 2.0f), 2.0f), 16.0f));
    P[11] = cb;
    P[12] = 1.0f / cb;
    // layer 10: angle = w10 * f32(pi) rounded once; cos/sin of that exact f32
    // in DOUBLE then rounded -> correctly-rounded f32 (matches numpy; OCML's
    // 1-2ulp f32 trig flipped |rot|<3 on border px -> round-1's 0.10 absmax).
    float ang = __fmul_rn(w10, 3.14159265358979323846f);
    P[13] = (float)cos((double)ang);                    // ca
    P[14] = (float)sin((double)ang);                    // sa
    P[15] = w11;
    P[16] = w12 * 0.1f;                                 // k12
    P[17] = w13 * 0.05f;                                // k13
    P[18] = 1.0f + w14;                                 // con
    P[19] = w15;
}

// sin(2*pi*rev): v_fract_f32 + v_sin_f32
__device__ __forceinline__ float hsin(float rev) {
    return __builtin_amdgcn_sinf(__builtin_amdgcn_fractf(rev));
}

// Exact floor(x/cb) for integer-valued x in [0,32), cb in [2,16].
__device__ __forceinline__ float fdivq(float xf, float cb, float rcb) {
    float q = floorf(xf * rcb);
    q += ((q + 1.0f) * cb <= xf) ? 1.0f : 0.0f;
    q -= ((q * cb) > xf) ? 1.0f : 0.0f;
    return q;
}

// Wave64 min/max reduction on the VALU pipe via DPP (row_shr 1/2/4/8 +
// row_bcast:15/31, then readlane 63). dpp_ctrl must be an ICE -> template.
template <int CTRL>
__device__ __forceinline__ float dpp_step_min(float v) {
    int i = __float_as_int(v);
    int s = __builtin_amdgcn_update_dpp(i, i, CTRL, 0xf, 0xf, false);
    return fminf(v, __int_as_float(s));
}
template <int CTRL>
__device__ __forceinline__ float dpp_step_max(float v) {
    int i = __float_as_int(v);
    int s = __builtin_amdgcn_update_dpp(i, i, CTRL, 0xf, 0xf, false);
    return fmaxf(v, __int_as_float(s));
}

// One block = one image. Thread t: x = t>>3 FIXED, y = 4(t&7)..+3.
// BARRIER-FREE main path: no LDS tables, no setup phase — every thread
// computes its own X/Y/stab values in REGISTERS (redundant VALU, but removes
// both barriers + all LDS reads + the 2-waves-compute/2-idle setup phase;
// global loads issued at entry can overlap the whole register setup).
// All bit-critical chains use instruction sequences identical to the
// LDS version -> values bitwise unchanged. One barrier remains (cross-wave
// min/max reduce).
__global__ __launch_bounds__(256) void decode_kernel(
        const float* __restrict__ nrand,   // noise_randn
        const float* __restrict__ nunif,   // noise_rand
        float* __restrict__ out) {
    int b = blockIdx.x;
    int t = threadIdx.x;

    // entry: issue all global loads (no barrier between issue and use)
    size_t q = (size_t)b * 256 + (size_t)t;    // float4 index
    float4 R  = ((const float4*)g_r)[t];
    float4 TH = ((const float4*)g_th)[t];
    float4 NR = ((const float4*)nrand)[q];
    float4 NU = ((const float4*)nunif)[q];

    const float4* Pq = (const float4*)(g_par + (size_t)b * PSTRIDE);
    float4 q0 = Pq[0], q1 = Pq[1], q2 = Pq[2], q3 = Pq[3], q4 = Pq[4];
    float a0 = q0.x, lo = q0.y, hi = q0.z, s2 = q0.w;
    float s3 = q1.x, s4 = q1.y, s5o = q1.z, w6 = q1.w;
    float bxy = q2.x, nk = q2.y, t8 = q2.z, cb = q2.w;
    float rcb = q3.x, ca = q3.y, sa = q3.z, w11 = q3.w;
    float k12 = q4.x, k13 = q4.y, con = q4.z, w15 = q4.w;

    int x  = t >> 3;
    int y0 = (t & 7) * 4;
    float xf = (float)x;

    // ---- X-side, once per thread (identical op sequence to LDS version) ----
    float qx   = fdivq(xf, cb, rcb);
    float px   = qx - 2.0f * floorf(qx * 0.5f);       // parity 0/1, exact
    float dxx  = xf - bxy;
    float xsum = 0.5f * hsin(s2 * xf) + 0.3f * px;
    float xmv  = (xf >= lo && xf < hi) ? 1.0f : 0.0f;
    float mpx  = -0.6f * px;
    float gx   = __expf(dxx * dxx * nk);
    float rxv  = __fmul_rn(ca, xf - 16.0f);

    // ---- Y-side + stab, 4 values in registers (fully unrolled) ----
    float ysv[4], ymv[4], pyv[4], gyv[4], syv[4], stv[4];
#pragma unroll
    for (int i = 0; i < 4; ++i) {
        int   y  = y0 + i;
        float yf = (float)y;
        float qy = fdivq(yf, cb, rcb);
        float py = qy - 2.0f * floorf(qy * 0.5f);
        float d  = yf - bxy;
        ysv[i] = 0.5f * hsin(s3 * yf) + 0.5f * hsin(0.015625f * yf + s5o)
                 + 0.3f * py + w6 - 0.5f * k13;
        ymv[i] = (yf >= lo && yf < hi) ? 0.5f : 0.0f;
        pyv[i] = py;
        gyv[i] = __expf(d * d * nk);
        syv[i] = __fmul_rn(sa, yf - 16.0f);
        stv[i] = 0.5f * hsin(s4 * (float)(x + y));
    }

    v2f ysA = {ysv[0], ysv[1]}, ysB = {ysv[2], ysv[3]};
    v2f ymA = {ymv[0], ymv[1]}, ymB = {ymv[2], ymv[3]};
    v2f pyA = {pyv[0], pyv[1]}, pyB = {pyv[2], pyv[3]};
    v2f gyA = {gyv[0], gyv[1]}, gyB = {gyv[2], gyv[3]};
    v2f syA = {syv[0], syv[1]}, syB = {syv[2], syv[3]};
    v2f stA = {stv[0], stv[1]}, stB = {stv[2], stv[3]};

    const v2f m1   = {-1.0f, -1.0f};
    const v2f a02  = {a0, a0};
    const v2f xs2  = {xsum, xsum};
    const v2f xm2  = {xmv, xmv};
    const v2f px2  = {mpx, mpx};
    const v2f gx2  = {gx, gx};
    const v2f rx2  = {rxv, rxv};
    const v2f nt82 = {-t8, -t8};
    const v2f w112 = {w11, w11};
    const v2f h2   = {0.5f, 0.5f};
    const v2f k122 = {k12, k12};
    const v2f k132 = {k13, k13};

    v2f i01, i23;
    float mn, mx;

#pragma unroll
    for (int k = 0; k < 2; ++k) {
        v2f r2  = k ? (v2f){R.z, R.w}   : (v2f){R.x, R.y};
        v2f th2 = k ? (v2f){TH.z, TH.w} : (v2f){TH.x, TH.y};
        v2f nr2 = k ? (v2f){NR.z, NR.w} : (v2f){NR.x, NR.y};
        v2f nu2 = k ? (v2f){NU.z, NU.w} : (v2f){NU.x, NU.y};
        v2f ys = k ? ysB : ysA, ym = k ? ymB : ymA, py = k ? pyB : pyA;
        v2f gy = k ? gyB : gyA, sy = k ? syB : syA, st = k ? stB : stA;

        v2f v;
        PK_FMA_CLAMP(v, r2, m1, a02);   // layer 0: clip(a0 - r, 0, 1)
        PK_ADD_ACC(v, ys);              // sin3+warp+0.3py+bias-0.5k13
        PK_ADD_ACC(v, xs2);             // sin2+0.3px
        PK_ADD_ACC(v, st);              // diagonal sinusoid
        PK_FMA_ACC(v, xm2, ym);         // layer 1: square (exact masks)
        PK_FMA_ACC(v, px2, py);         // checker cross: -0.6*px*py (exact)
        PK_FMA_ACC(v, gx2, gy);         // gaussian split (<=4e-7)
        v2f dr, dr2, rot, ang;
        PK_ADD(dr, r2, nt82);           // RN(r - t8)  == __fsub_rn
        PK_MUL(dr2, dr, dr);            // RN(dr*dr)   == __fmul_rn
        PK_ADD(rot, sy, rx2);           // RN(ca(x-16) + sa(y-16))
        PK_MUL(ang, th2, w112);
        v2f sn = {hsin(ang.x), hsin(ang.y)};
        PK_FMA_ACC(v, sn, h2);          // angular sinusoid
        PK_FMA_ACC(v, nr2, k122);       // noise_randn
        PK_FMA_ACC(v, nu2, k132);       // noise_rand (-0.5k13 in ysum)

        // discrete mask adds: scalar, bit-exact compare inputs from pk RN ops
        float vx = v.x + ((dr2.x < 10.0f) ? 1.0f : 0.0f);
        float vy = v.y + ((dr2.y < 10.0f) ? 1.0f : 0.0f);
        vx += (fabsf(rot.x) < 3.0f) ? 0.6f : 0.0f;
        vy += (fabsf(rot.y) < 3.0f) ? 0.6f : 0.0f;

        v2f r_ = {vx, vy};
        if (k == 0) { i01 = r_; mn = fminf(vx, vy); mx = fmaxf(vx, vy); }
        else        { i23 = r_; mn = fminf(mn, fminf(vx, vy));
                                mx = fmaxf(mx, fmaxf(vx, vy)); }
    }

    // wave64 reduce on VALU pipe (DPP), result via lane 63
    mn = dpp_step_min<0x111>(mn);   // row_shr:1
    mx = dpp_step_max<0x111>(mx);
    mn = dpp_step_min<0x112>(mn);   // row_shr:2
    mx = dpp_step_max<0x112>(mx);
    mn = dpp_step_min<0x114>(mn);   // row_shr:4
    mx = dpp_step_max<0x114>(mx);
    mn = dpp_step_min<0x118>(mn);   // row_shr:8
    mx = dpp_step_max<0x118>(mx);
    mn = dpp_step_min<0x142>(mn);   // row_bcast:15
    mx = dpp_step_max<0x142>(mx);
    mn = dpp_step_min<0x143>(mn);   // row_bcast:31
    mx = dpp_step_max<0x143>(mx);
    mn = __int_as_float(__builtin_amdgcn_readlane(__float_as_int(mn), 63));
    mx = __int_as_float(__builtin_amdgcn_readlane(__float_as_int(mx), 63));

    // the single remaining barrier: cross-wave min/max
    __shared__ float smn[4], smx[4];
    int wid = t >> 6;
    if ((t & 63) == 0) { smn[wid] = mn; smx[wid] = mx; }
    __syncthreads();
    mn = fminf(fminf(smn[0], smn[1]), fminf(smn[2], smn[3]));
    mx = fmaxf(fmaxf(smx[0], smx[1]), fmaxf(smx[2], smx[3]));

    // contrast (v-0.5)*con+0.5, optional inversion, min-max normalize:
    // affine => o = v*sgn + c0; flips tracked by signs of con and w15.
    float ac    = fabsf(con);
    float denom = fmaf(ac, mx - mn, 1e-8f);
    float s     = ac / denom;
    bool  eff   = (w15 > 0.0f) != (con < 0.0f);
    float bse   = eff ? mx : mn;
    float sgn   = eff ? -s : s;
    v2f c12 = {sgn, sgn};
    v2f c02 = {-bse * sgn, -bse * sgn};

    v2f o01, o23;
    PK_FMA(o01, i01, c12, c02);
    PK_FMA(o23, i23, c12, c02);
    float4 O = {o01.x, o01.y, o23.x, o23.y};
    ((float4*)out)[q] = O;
}

extern "C" void kernel_launch(void* const* d_in, const int* in_sizes, int n_in,
                              void* d_out, int out_size, void* d_ws, size_t ws_size,
                              hipStream_t stream) {
    const float* W  = (const float*)d_in[0];
    const float* nr = (const float*)d_in[1];
    const float* nu = (const float*)d_in[2];
    float* out = (float*)d_out;

    init_params_kernel<<<NB / 256, 256, 0, stream>>>(W);
    decode_kernel<<<NB, 256, 0, stream>>>(nr, nu, out);
}

// Round 15
// 164.885 us; speedup vs baseline: 1.0263x; 1.0263x over previous
//
#include <hip/hip_runtime.h>
#include <math.h>

#define NB 65536
#define IMGD 32
#define NPIX 1024
#define PSTRIDE 20

typedef float v2f __attribute__((ext_vector_type(2)));

// Packed FP32 (VOP3P, full-rate on CDNA3/4). Compiler never forms these from
// scalar f32 -> emit directly. 64-bit "v" operands = aligned VGPR pairs.
#define PK_FMA(d, a, b, c) \
    asm("v_pk_fma_f32 %0, %1, %2, %3" : "=v"(d) : "v"(a), "v"(b), "v"(c))
#define PK_FMA_CLAMP(d, a, b, c) \
    asm("v_pk_fma_f32 %0, %1, %2, %3 clamp" : "=v"(d) : "v"(a), "v"(b), "v"(c))
#define PK_FMA_ACC(acc, a, b) \
    asm("v_pk_fma_f32 %0, %1, %2, %0" : "+v"(acc) : "v"(a), "v"(b))
#define PK_ADD(d, a, b) \
    asm("v_pk_add_f32 %0, %1, %2" : "=v"(d) : "v"(a), "v"(b))
#define PK_ADD_ACC(acc, a) \
    asm("v_pk_add_f32 %0, %0, %1" : "+v"(acc) : "v"(a))
#define PK_MUL(d, a, b) \
    asm("v_pk_mul_f32 %0, %1, %2" : "=v"(d) : "v"(a), "v"(b))

// Constant theta table and per-image derived params. (g_r table removed:
// r is recomputed inline bitwise-identically — exact integer sum + correctly
// rounded sqrtf, same device instructions as before.)
__device__ __align__(16) float g_th[NPIX];   // theta * 5/(2*pi)
__device__ __align__(16) float g_par[(size_t)NB * PSTRIDE];

__global__ void init_params_kernel(const float* __restrict__ W) {
    int b = blockIdx.x * blockDim.x + threadIdx.x;

    // block 0 additionally fills the constant theta table (4 px/thread)
    if (blockIdx.x == 0) {
        int t = threadIdx.x;
        for (int k = 0; k < 4; ++k) {
            int p = t * 4 + k;
            int x = p >> 5, y = p & 31;
            float dx = (float)(x - 16), dy = (float)(y - 16);
            // theta = atan2(yy-CY, xx-CX); fold 5/(2*pi) for revolution sin
            g_th[p] = atan2f(dy, dx) * 0.79577471545947668f;
        }
    }
    if (b >= NB) return;
    const float* w = W + (size_t)b * 16;
    float* P = g_par + (size_t)b * PSTRIDE;

    float w0 = w[0], w1 = w[1], w2 = w[2], w3 = w[3], w4 = w[4], w5 = w[5],
          w6 = w[6], w7 = w[7], w8 = w[8], w9 = w[9], w10 = w[10], w11 = w[11],
          w12 = w[12], w13 = w[13], w14 = w[14], w15 = w[15];

    P[0] = w0 * 5.0f;                                   // a0
    // layer 1: half = floor(clip(|w1|*8, 2, 12)); |w1|*8 exact (pow2 mul)
    float half = floorf(fminf(fmaxf(fabsf(w1) * 8.0f, 2.0f), 12.0f));
    P[1] = 16.0f - half;                                // lo (exact)
    P[2] = 16.0f + half;                                // hi (exact)
    P[3] = w2 * 0.15625f;                               // s2 (10/64 rev)
    P[4] = w3 * 0.15625f;                               // s3
    P[5] = w4 * 0.0390625f;                             // s4 (5/128 rev)
    P[6] = w5 * 0.15625f;                               // s5o
    P[7] = w6;                                          // bias
    // layer 7 blob center: trunc(16 + w7*5), mul/add un-fused to match ref
    float t7 = __fadd_rn(16.0f, __fmul_rn(w7, 5.0f));
    P[8] = truncf(t7);                                  // bxy
    float sg = 4.0f + fabsf(w7) * 4.0f;
    P[9] = -1.0f / (2.0f * sg * sg);                    // nk
    P[10] = w8 * 10.0f;                                 // t8 (single mul)
    // layer 9: cb = floor(clip(|w9|*8 + 2, 2, 16)); exact chain
    float cb = floorf(fminf(fmaxf(__fadd_rn(fabsf(w9) * 8.0f, 2.0f), 2.0f), 16.0f));
    P[11] = cb;
    P[12] = 1.0f / cb;
    // layer 10: angle = w10 * f32(pi) rounded once; cos/sin of that exact f32
    // in DOUBLE then rounded -> correctly-rounded f32 (matches numpy; OCML's
    // 1-2ulp f32 trig flipped |rot|<3 on border px -> round-1's 0.10 absmax).
    float ang = __fmul_rn(w10, 3.14159265358979323846f);
    P[13] = (float)cos((double)ang);                    // ca
    P[14] = (float)sin((double)ang);                    // sa
    P[15] = w11;
    P[16] = w12 * 0.1f;                                 // k12
    P[17] = w13 * 0.05f;                                // k13
    P[18] = 1.0f + w14;                                 // con
    P[19] = w15;
}

// sin(2*pi*rev): v_fract_f32 + v_sin_f32
__device__ __forceinline__ float hsin(float rev) {
    return __builtin_amdgcn_sinf(__builtin_amdgcn_fractf(rev));
}

// Exact floor(x/cb) for integer-valued x in [0,32), cb in [2,16].
__device__ __forceinline__ float fdivq(float xf, float cb, float rcb) {
    float q = floorf(xf * rcb);
    q += ((q + 1.0f) * cb <= xf) ? 1.0f : 0.0f;
    q -= ((q * cb) > xf) ? 1.0f : 0.0f;
    return q;
}

// Wave64 min/max reduction on the VALU pipe via DPP (row_shr 1/2/4/8 +
// row_bcast:15/31, then readlane 63). dpp_ctrl must be an ICE -> template.
template <int CTRL>
__device__ __forceinline__ float dpp_step_min(float v) {
    int i = __float_as_int(v);
    int s = __builtin_amdgcn_update_dpp(i, i, CTRL, 0xf, 0xf, false);
    return fminf(v, __int_as_float(s));
}
template <int CTRL>
__device__ __forceinline__ float dpp_step_max(float v) {
    int i = __float_as_int(v);
    int s = __builtin_amdgcn_update_dpp(i, i, CTRL, 0xf, 0xf, false);
    return fmaxf(v, __int_as_float(s));
}

// One block = one image. Thread t: x = t>>3 FIXED, y = 4(t&7)..+3.
// (Known-good round-11 structure; single change: r computed inline —
// exact integer fma sum + correctly-rounded sqrtf == bitwise table value —
// removing one dwordx4 load + waitcnt from the post-barrier chain.)
__global__ __launch_bounds__(256) void decode_kernel(
        const float* __restrict__ nrand,   // noise_randn
        const float* __restrict__ nunif,   // noise_rand
        float* __restrict__ out) {
    int b = blockIdx.x;
    int t = threadIdx.x;

    const float4* Pq = (const float4*)(g_par + (size_t)b * PSTRIDE);
    float4 q0 = Pq[0], q1 = Pq[1], q2 = Pq[2], q3 = Pq[3], q4 = Pq[4];
    float a0 = q0.x, lo = q0.y, hi = q0.z, s2 = q0.w;
    float s3 = q1.x, s4 = q1.y, s5o = q1.z, w6 = q1.w;
    float bxy = q2.x, nk = q2.y, t8 = q2.z, cb = q2.w;
    float rcb = q3.x, ca = q3.y, sa = q3.z, w11 = q3.w;
    float k12 = q4.x, k13 = q4.y, con = q4.z, w15 = q4.w;

    __shared__ float4 xt4[32];     // {xsum=0.5sin2+0.3px, xm(0/1), -0.6px, gx}
    __shared__ float  rx[32];      // ca*(x-16) un-fused
    __shared__ float  ysum[32];    // 0.5sin3+0.5warp+0.3py+w6-0.5k13
    __shared__ float  ym05[32];    // square y mask (0/0.5)
    __shared__ float  pyt[32];     // checker y parity (0/1)
    __shared__ float  gyt[32];     // exp(nk*dy^2)
    __shared__ float  syt[32];     // sa*(y-16) un-fused
    __shared__ float  stab[63];    // 0.5*sin4(x+y)

    if (t < 32) {
        float xf = (float)t;
        float qx = fdivq(xf, cb, rcb);
        float px = qx - 2.0f * floorf(qx * 0.5f);       // parity 0/1, exact
        float d  = xf - bxy;
        float4 e;
        e.x = 0.5f * hsin(s2 * xf) + 0.3f * px;
        e.y = (xf >= lo && xf < hi) ? 1.0f : 0.0f;
        e.z = -0.6f * px;
        e.w = __expf(d * d * nk);
        xt4[t] = e;
        rx[t] = __fmul_rn(ca, xf - 16.0f);
    } else if (t < 64) {
        int   y  = t - 32;
        float yf = (float)y;
        float qy = fdivq(yf, cb, rcb);
        float py = qy - 2.0f * floorf(qy * 0.5f);
        float d  = yf - bxy;
        ysum[y] = 0.5f * hsin(s3 * yf) + 0.5f * hsin(0.015625f * yf + s5o)
                  + 0.3f * py + w6 - 0.5f * k13;
        ym05[y] = (yf >= lo && yf < hi) ? 0.5f : 0.0f;
        pyt[y]  = py;
        gyt[y]  = __expf(d * d * nk);
        syt[y]  = __fmul_rn(sa, yf - 16.0f);
    } else if (t < 127) {
        int s = t - 64;
        stab[s] = 0.5f * hsin(s4 * (float)s);
    }
    __syncthreads();

    int x  = t >> 3;
    int y0 = (t & 7) * 4;

    float4 X   = xt4[x];
    float  rxv = rx[x];

    // inline r: dx2, dy*dy exact integer squares; fmaf sum exact (<=512);
    // sqrtf correctly rounded -> bitwise equal to the former g_r table.
    float dxr = (float)(x - 16);
    float dx2 = dxr * dxr;
    float r4[4];
#pragma unroll
    for (int j = 0; j < 4; ++j) {
        float dyr = (float)(y0 + j - 16);
        r4[j] = sqrtf(fmaf(dyr, dyr, dx2));
    }

    // y-pair tables: aligned ds_read_b64, same-addr broadcast across lanes
    v2f ysA = *(const v2f*)&ysum[y0], ysB = *(const v2f*)&ysum[y0 + 2];
    v2f ymA = *(const v2f*)&ym05[y0], ymB = *(const v2f*)&ym05[y0 + 2];
    v2f pyA = *(const v2f*)&pyt[y0],  pyB = *(const v2f*)&pyt[y0 + 2];
    v2f gyA = *(const v2f*)&gyt[y0],  gyB = *(const v2f*)&gyt[y0 + 2];
    v2f syA = *(const v2f*)&syt[y0],  syB = *(const v2f*)&syt[y0 + 2];
    int s0 = x + y0;
    v2f stA = {stab[s0], stab[s0 + 1]}, stB = {stab[s0 + 2], stab[s0 + 3]};

    size_t q = (size_t)b * 256 + (size_t)t;    // float4 index
    float4 TH = ((const float4*)g_th)[t];
    float4 NR = ((const float4*)nrand)[q];
    float4 NU = ((const float4*)nunif)[q];

    const v2f m1   = {-1.0f, -1.0f};
    const v2f a02  = {a0, a0};
    const v2f xs2  = {X.x, X.x};
    const v2f xm2  = {X.y, X.y};
    const v2f px2  = {X.z, X.z};
    const v2f gx2  = {X.w, X.w};
    const v2f rx2  = {rxv, rxv};
    const v2f nt82 = {-t8, -t8};
    const v2f w112 = {w11, w11};
    const v2f h2   = {0.5f, 0.5f};
    const v2f k122 = {k12, k12};
    const v2f k132 = {k13, k13};

    v2f i01, i23;
    float mn, mx;

#pragma unroll
    for (int k = 0; k < 2; ++k) {
        v2f r2  = k ? (v2f){r4[2], r4[3]} : (v2f){r4[0], r4[1]};
        v2f th2 = k ? (v2f){TH.z, TH.w} : (v2f){TH.x, TH.y};
        v2f nr2 = k ? (v2f){NR.z, NR.w} : (v2f){NR.x, NR.y};
        v2f nu2 = k ? (v2f){NU.z, NU.w} : (v2f){NU.x, NU.y};
        v2f ys = k ? ysB : ysA, ym = k ? ymB : ymA, py = k ? pyB : pyA;
        v2f gy = k ? gyB : gyA, sy = k ? syB : syA, st = k ? stB : stA;

        v2f v;
        PK_FMA_CLAMP(v, r2, m1, a02);   // layer 0: clip(a0 - r, 0, 1)
        PK_ADD_ACC(v, ys);              // sin3+warp+0.3py+bias-0.5k13
        PK_ADD_ACC(v, xs2);             // sin2+0.3px
        PK_ADD_ACC(v, st);              // diagonal sinusoid
        PK_FMA_ACC(v, xm2, ym);         // layer 1: square (exact masks)
        PK_FMA_ACC(v, px2, py);         // checker cross: -0.6*px*py (exact)
        PK_FMA_ACC(v, gx2, gy);         // gaussian split (<=4e-7)
        v2f dr, dr2, rot, ang;
        PK_ADD(dr, r2, nt82);           // RN(r - t8)  == __fsub_rn
        PK_MUL(dr2, dr, dr);            // RN(dr*dr)   == __fmul_rn
        PK_ADD(rot, sy, rx2);           // RN(ca(x-16) + sa(y-16))
        PK_MUL(ang, th2, w112);
        v2f sn = {hsin(ang.x), hsin(ang.y)};
        PK_FMA_ACC(v, sn, h2);          // angular sinusoid
        PK_FMA_ACC(v, nr2, k122);       // noise_randn
        PK_FMA_ACC(v, nu2, k132);       // noise_rand (-0.5k13 in ysum)

        // discrete mask adds: scalar, bit-exact compare inputs from pk RN ops
        float vx = v.x + ((dr2.x < 10.0f) ? 1.0f : 0.0f);
        float vy = v.y + ((dr2.y < 10.0f) ? 1.0f : 0.0f);
        vx += (fabsf(rot.x) < 3.0f) ? 0.6f : 0.0f;
        vy += (fabsf(rot.y) < 3.0f) ? 0.6f : 0.0f;

        v2f r_ = {vx, vy};
        if (k == 0) { i01 = r_; mn = fminf(vx, vy); mx = fmaxf(vx, vy); }
        else        { i23 = r_; mn = fminf(mn, fminf(vx, vy));
                                mx = fmaxf(mx, fmaxf(vx, vy)); }
    }

    // wave64 reduce on VALU pipe (DPP), result via lane 63
    mn = dpp_step_min<0x111>(mn);   // row_shr:1
    mx = dpp_step_max<0x111>(mx);
    mn = dpp_step_min<0x112>(mn);   // row_shr:2
    mx = dpp_step_max<0x112>(mx);
    mn = dpp_step_min<0x114>(mn);   // row_shr:4
    mx = dpp_step_max<0x114>(mx);
    mn = dpp_step_min<0x118>(mn);   // row_shr:8
    mx = dpp_step_max<0x118>(mx);
    mn = dpp_step_min<0x142>(mn);   // row_bcast:15
    mx = dpp_step_max<0x142>(mx);
    mn = dpp_step_min<0x143>(mn);   // row_bcast:31
    mx = dpp_step_max<0x143>(mx);
    mn = __int_as_float(__builtin_amdgcn_readlane(__float_as_int(mn), 63));
    mx = __int_as_float(__builtin_amdgcn_readlane(__float_as_int(mx), 63));

    __shared__ float smn[4], smx[4];
    int wid = t >> 6;
    if ((t & 63) == 0) { smn[wid] = mn; smx[wid] = mx; }
    __syncthreads();
    mn = fminf(fminf(smn[0], smn[1]), fminf(smn[2], smn[3]));
    mx = fmaxf(fmaxf(smx[0], smx[1]), fmaxf(smx[2], smx[3]));

    // contrast (v-0.5)*con+0.5, optional inversion, min-max normalize:
    // affine => o = v*sgn + c0; flips tracked by signs of con and w15.
    float ac    = fabsf(con);
    float denom = fmaf(ac, mx - mn, 1e-8f);
    float s     = ac / denom;
    bool  eff   = (w15 > 0.0f) != (con < 0.0f);
    float bse   = eff ? mx : mn;
    float sgn   = eff ? -s : s;
    v2f c12 = {sgn, sgn};
    v2f c02 = {-bse * sgn, -bse * sgn};

    v2f o01, o23;
    PK_FMA(o01, i01, c12, c02);
    PK_FMA(o23, i23, c12, c02);
    float4 O = {o01.x, o01.y, o23.x, o23.y};
    ((float4*)out)[q] = O;
}

extern "C" void kernel_launch(void* const* d_in, const int* in_sizes, int n_in,
                              void* d_out, int out_size, void* d_ws, size_t ws_size,
                              hipStream_t stream) {
    const float* W  = (const float*)d_in[0];
    const float* nr = (const float*)d_in[1];
    const float* nu = (const float*)d_in[2];
    float* out = (float*)d_out;

    init_params_kernel<<<NB / 256, 256, 0, stream>>>(W);
    decode_kernel<<<NB, 256, 0, stream>>>(nr, nu, out);
}

// Round 16
// 160.299 us; speedup vs baseline: 1.0556x; 1.0286x over previous
//
#include <hip/hip_runtime.h>
#include <math.h>

#define NB 65536
#define NPIX 1024
#define PSTRIDE 20
#define IPB 8                    // images per block (pipelined)
#define NBLK (NB / IPB)

typedef float v2f __attribute__((ext_vector_type(2)));

// Packed FP32 (VOP3P, full-rate on CDNA3/4). Compiler never forms these from
// scalar f32 -> emit directly. 64-bit "v" operands = aligned VGPR pairs.
#define PK_FMA(d, a, b, c) \
    asm("v_pk_fma_f32 %0, %1, %2, %3" : "=v"(d) : "v"(a), "v"(b), "v"(c))
#define PK_FMA_CLAMP(d, a, b, c) \
    asm("v_pk_fma_f32 %0, %1, %2, %3 clamp" : "=v"(d) : "v"(a), "v"(b), "v"(c))
#define PK_FMA_ACC(acc, a, b) \
    asm("v_pk_fma_f32 %0, %1, %2, %0" : "+v"(acc) : "v"(a), "v"(b))
#define PK_ADD(d, a, b) \
    asm("v_pk_add_f32 %0, %1, %2" : "=v"(d) : "v"(a), "v"(b))
#define PK_ADD_ACC(acc, a) \
    asm("v_pk_add_f32 %0, %0, %1" : "+v"(acc) : "v"(a))
#define PK_MUL(d, a, b) \
    asm("v_pk_mul_f32 %0, %1, %2" : "=v"(d) : "v"(a), "v"(b))

__device__ __align__(16) float g_r[NPIX];
__device__ __align__(16) float g_th[NPIX];   // theta * 5/(2*pi)
__device__ __align__(16) float g_par[(size_t)NB * PSTRIDE];

__global__ void init_params_kernel(const float* __restrict__ W) {
    int b = blockIdx.x * blockDim.x + threadIdx.x;

    if (blockIdx.x == 0) {
        int t = threadIdx.x;
        for (int k = 0; k < 4; ++k) {
            int p = t * 4 + k;
            int x = p >> 5, y = p & 31;
            float dx = (float)(x - 16), dy = (float)(y - 16);
            g_r[p] = sqrtf(dx * dx + dy * dy);            // exact -> bitwise
            g_th[p] = atan2f(dy, dx) * 0.79577471545947668f;
        }
    }
    if (b >= NB) return;
    const float* w = W + (size_t)b * 16;
    float* P = g_par + (size_t)b * PSTRIDE;

    float w0 = w[0], w1 = w[1], w2 = w[2], w3 = w[3], w4 = w[4], w5 = w[5],
          w6 = w[6], w7 = w[7], w8 = w[8], w9 = w[9], w10 = w[10], w11 = w[11],
          w12 = w[12], w13 = w[13], w14 = w[14], w15 = w[15];

    P[0] = w0 * 5.0f;                                   // a0
    float half = floorf(fminf(fmaxf(fabsf(w1) * 8.0f, 2.0f), 12.0f));
    P[1] = 16.0f - half;                                // lo (exact)
    P[2] = 16.0f + half;                                // hi (exact)
    P[3] = w2 * 0.15625f;                               // s2 (10/64 rev)
    P[4] = w3 * 0.15625f;                               // s3
    P[5] = w4 * 0.0390625f;                             // s4 (5/128 rev)
    P[6] = w5 * 0.15625f;                               // s5o
    P[7] = w6;                                          // bias
    float t7 = __fadd_rn(16.0f, __fmul_rn(w7, 5.0f));   // un-fused: match ref
    P[8] = truncf(t7);                                  // bxy
    float sg = 4.0f + fabsf(w7) * 4.0f;
    P[9] = -1.0f / (2.0f * sg * sg);                    // nk
    P[10] = w8 * 10.0f;                                 // t8 (single mul)
    float cb = floorf(fminf(fmaxf(__fadd_rn(fabsf(w9) * 8.0f, 2.0f), 2.0f), 16.0f));
    P[11] = cb;
    P[12] = 1.0f / cb;
    // correctly-rounded cos/sin of exact-f32 angle (matches numpy; OCML f32
    // trig is 1-2ulp -> flipped |rot|<3 borders -> round-1's 0.10 absmax)
    float ang = __fmul_rn(w10, 3.14159265358979323846f);
    P[13] = (float)cos((double)ang);                    // ca
    P[14] = (float)sin((double)ang);                    // sa
    P[15] = w11;
    P[16] = w12 * 0.1f;                                 // k12
    P[17] = w13 * 0.05f;                                // k13
    P[18] = 1.0f + w14;                                 // con
    P[19] = w15;
}

__device__ __forceinline__ float hsin(float rev) {
    return __builtin_amdgcn_sinf(__builtin_amdgcn_fractf(rev));
}

__device__ __forceinline__ float fdivq(float xf, float cb, float rcb) {
    float q = floorf(xf * rcb);
    q += ((q + 1.0f) * cb <= xf) ? 1.0f : 0.0f;
    q -= ((q * cb) > xf) ? 1.0f : 0.0f;
    return q;
}

template <int CTRL>
__device__ __forceinline__ float dpp_step_min(float v) {
    int i = __float_as_int(v);
    int s = __builtin_amdgcn_update_dpp(i, i, CTRL, 0xf, 0xf, false);
    return fminf(v, __int_as_float(s));
}
template <int CTRL>
__device__ __forceinline__ float dpp_step_max(float v) {
    int i = __float_as_int(v);
    int s = __builtin_amdgcn_update_dpp(i, i, CTRL, 0xf, 0xf, false);
    return fmaxf(v, __int_as_float(s));
}

// Per-image LDS table setup — byte-for-byte the R11 sequences.
// Flat layout (floats): xt4 0..127 | rx 128..159 | ysum 160..191 |
// ym05 192..223 | pyt 224..255 | gyt 256..287 | syt 288..319 | stab 320..382
__device__ __forceinline__ void table_setup(float* __restrict__ L, int t,
        float4 q0, float4 q1, float4 q2, float4 q3, float4 q4) {
    float lo = q0.y, hi = q0.z, s2 = q0.w;
    float s3 = q1.x, s4 = q1.y, s5o = q1.z, w6 = q1.w;
    float bxy = q2.x, nk = q2.y, cb = q2.w;
    float rcb = q3.x, ca = q3.y, sa = q3.z;
    float k13 = q4.y;

    if (t < 32) {
        float xf = (float)t;
        float qx = fdivq(xf, cb, rcb);
        float px = qx - 2.0f * floorf(qx * 0.5f);       // parity 0/1, exact
        float d  = xf - bxy;
        float4 e;
        e.x = 0.5f * hsin(s2 * xf) + 0.3f * px;
        e.y = (xf >= lo && xf < hi) ? 1.0f : 0.0f;
        e.z = -0.6f * px;
        e.w = __expf(d * d * nk);
        ((float4*)L)[t] = e;
        L[128 + t] = __fmul_rn(ca, xf - 16.0f);
    } else if (t < 64) {
        int   y  = t - 32;
        float yf = (float)y;
        float qy = fdivq(yf, cb, rcb);
        float py = qy - 2.0f * floorf(qy * 0.5f);
        float d  = yf - bxy;
        L[160 + y] = 0.5f * hsin(s3 * yf) + 0.5f * hsin(0.015625f * yf + s5o)
                     + 0.3f * py + w6 - 0.5f * k13;
        L[192 + y] = (yf >= lo && yf < hi) ? 0.5f : 0.0f;
        L[224 + y] = py;
        L[256 + y] = __expf(d * d * nk);
        L[288 + y] = __fmul_rn(sa, yf - 16.0f);
    } else if (t < 127) {
        int s = t - 64;
        L[320 + s] = 0.5f * hsin(s4 * (float)s);
    }
}

// One block = IPB images, software-pipelined. Per image the structure is
// EXACTLY round-11 (known-good): tables in LDS, pk-asm additive chain, DPP
// reduce, folded epilogue. New: double-buffered tables; NR/NU for image i+1
// issued one full barrier-period before use (~1000cy of cover); params for
// i+2 prefetched scalar; g_r/g_th loaded ONCE per block into registers.
__global__ __launch_bounds__(256) void decode_kernel(
        const float* __restrict__ nrand,
        const float* __restrict__ nunif,
        float* __restrict__ out) {
    int t = threadIdx.x;
    int base = blockIdx.x * IPB;

    int x  = t >> 3;
    int y0 = (t & 7) * 4;

    // image-invariant per-thread constants (one load per block, not per image)
    float4 Rr  = ((const float4*)g_r)[t];
    float4 THr = ((const float4*)g_th)[t];

    __shared__ __align__(16) float lds[2][384];
    __shared__ float smn[4], smx[4];

    // params: current (c) and next (n) — uniform scalar loads
    float4 c0, c1, c2, c3, c4, n0, n1, n2, n3, n4;
    {
        const float4* P = (const float4*)(g_par + (size_t)base * PSTRIDE);
        c0 = P[0]; c1 = P[1]; c2 = P[2]; c3 = P[3]; c4 = P[4];
        const float4* Q = (const float4*)(g_par + (size_t)(base + 1) * PSTRIDE);
        n0 = Q[0]; n1 = Q[1]; n2 = Q[2]; n3 = Q[3]; n4 = Q[4];
    }
    size_t qi = (size_t)base * 256 + (size_t)t;
    float4 NRc = ((const float4*)nrand)[qi];
    float4 NUc = ((const float4*)nunif)[qi];

    table_setup(&lds[0][0], t, c0, c1, c2, c3, c4);
    __syncthreads();

    int cur = 0;
#pragma unroll 1
    for (int i = 0; i < IPB; ++i) {
        bool more = (i + 1 < IPB);
        float4 NRn, NUn;
        if (more) {
            // issue next image's loads NOW — consumed after the next barrier
            size_t qn = (size_t)(base + i + 1) * 256 + (size_t)t;
            NRn = ((const float4*)nrand)[qn];
            NUn = ((const float4*)nunif)[qn];
            // build next image's tables into the other LDS half
            table_setup(&lds[cur ^ 1][0], t, n0, n1, n2, n3, n4);
        }

        // ---- compute image base+i from lds[cur] (R11 body, verbatim) ----
        const float* L = &lds[cur][0];
        float a0 = c0.x, t8 = c2.z, w11 = c3.w;
        float k12 = c4.x, k13 = c4.y, con = c4.z, w15 = c4.w;

        float4 X   = *(const float4*)&L[4 * x];
        float  rxv = L[128 + x];
        v2f ysA = *(const v2f*)&L[160 + y0], ysB = *(const v2f*)&L[160 + y0 + 2];
        v2f ymA = *(const v2f*)&L[192 + y0], ymB = *(const v2f*)&L[192 + y0 + 2];
        v2f pyA = *(const v2f*)&L[224 + y0], pyB = *(const v2f*)&L[224 + y0 + 2];
        v2f gyA = *(const v2f*)&L[256 + y0], gyB = *(const v2f*)&L[256 + y0 + 2];
        v2f syA = *(const v2f*)&L[288 + y0], syB = *(const v2f*)&L[288 + y0 + 2];
        int s0 = x + y0;
        v2f stA = {L[320 + s0], L[320 + s0 + 1]};
        v2f stB = {L[320 + s0 + 2], L[320 + s0 + 3]};

        const v2f m1   = {-1.0f, -1.0f};
        const v2f a02  = {a0, a0};
        const v2f xs2  = {X.x, X.x};
        const v2f xm2  = {X.y, X.y};
        const v2f px2  = {X.z, X.z};
        const v2f gx2  = {X.w, X.w};
        const v2f rx2  = {rxv, rxv};
        const v2f nt82 = {-t8, -t8};
        const v2f w112 = {w11, w11};
        const v2f h2   = {0.5f, 0.5f};
        const v2f k122 = {k12, k12};
        const v2f k132 = {k13, k13};

        v2f i01, i23;
        float mn, mx;

#pragma unroll
        for (int k = 0; k < 2; ++k) {
            v2f r2  = k ? (v2f){Rr.z, Rr.w}   : (v2f){Rr.x, Rr.y};
            v2f th2 = k ? (v2f){THr.z, THr.w} : (v2f){THr.x, THr.y};
            v2f nr2 = k ? (v2f){NRc.z, NRc.w} : (v2f){NRc.x, NRc.y};
            v2f nu2 = k ? (v2f){NUc.z, NUc.w} : (v2f){NUc.x, NUc.y};
            v2f ys = k ? ysB : ysA, ym = k ? ymB : ymA, py = k ? pyB : pyA;
            v2f gy = k ? gyB : gyA, sy = k ? syB : syA, st = k ? stB : stA;

            v2f v;
            PK_FMA_CLAMP(v, r2, m1, a02);   // layer 0: clip(a0 - r, 0, 1)
            PK_ADD_ACC(v, ys);              // sin3+warp+0.3py+bias-0.5k13
            PK_ADD_ACC(v, xs2);             // sin2+0.3px
            PK_ADD_ACC(v, st);              // diagonal sinusoid
            PK_FMA_ACC(v, xm2, ym);         // layer 1: square (exact masks)
            PK_FMA_ACC(v, px2, py);         // checker cross (exact)
            PK_FMA_ACC(v, gx2, gy);         // gaussian split (<=4e-7)
            v2f dr, dr2, rot, ang;
            PK_ADD(dr, r2, nt82);           // RN(r - t8)  == __fsub_rn
            PK_MUL(dr2, dr, dr);            // RN(dr*dr)   == __fmul_rn
            PK_ADD(rot, sy, rx2);           // RN(ca(x-16) + sa(y-16))
            PK_MUL(ang, th2, w112);
            v2f sn = {hsin(ang.x), hsin(ang.y)};
            PK_FMA_ACC(v, sn, h2);          // angular sinusoid
            PK_FMA_ACC(v, nr2, k122);       // noise_randn
            PK_FMA_ACC(v, nu2, k132);       // noise_rand

            float vx = v.x + ((dr2.x < 10.0f) ? 1.0f : 0.0f);
            float vy = v.y + ((dr2.y < 10.0f) ? 1.0f : 0.0f);
            vx += (fabsf(rot.x) < 3.0f) ? 0.6f : 0.0f;
            vy += (fabsf(rot.y) < 3.0f) ? 0.6f : 0.0f;

            v2f r_ = {vx, vy};
            if (k == 0) { i01 = r_; mn = fminf(vx, vy); mx = fmaxf(vx, vy); }
            else        { i23 = r_; mn = fminf(mn, fminf(vx, vy));
                                    mx = fmaxf(mx, fmaxf(vx, vy)); }
        }

        // wave64 DPP reduce, result via lane 63
        mn = dpp_step_min<0x111>(mn);  mx = dpp_step_max<0x111>(mx);
        mn = dpp_step_min<0x112>(mn);  mx = dpp_step_max<0x112>(mx);
        mn = dpp_step_min<0x114>(mn);  mx = dpp_step_max<0x114>(mx);
        mn = dpp_step_min<0x118>(mn);  mx = dpp_step_max<0x118>(mx);
        mn = dpp_step_min<0x142>(mn);  mx = dpp_step_max<0x142>(mx);
        mn = dpp_step_min<0x143>(mn);  mx = dpp_step_max<0x143>(mx);
        mn = __int_as_float(__builtin_amdgcn_readlane(__float_as_int(mn), 63));
        mx = __int_as_float(__builtin_amdgcn_readlane(__float_as_int(mx), 63));

        int wid = t >> 6;
        if ((t & 63) == 0) { smn[wid] = mn; smx[wid] = mx; }
        __syncthreads();                              // barrier A
        mn = fminf(fminf(smn[0], smn[1]), fminf(smn[2], smn[3]));
        mx = fmaxf(fmaxf(smx[0], smx[1]), fmaxf(smx[2], smx[3]));

        // contrast+inversion folded into normalize (affine)
        float ac    = fabsf(con);
        float denom = fmaf(ac, mx - mn, 1e-8f);
        float s     = ac / denom;
        bool  eff   = (w15 > 0.0f) != (con < 0.0f);
        float bse   = eff ? mx : mn;
        float sgn   = eff ? -s : s;
        v2f c12 = {sgn, sgn};
        v2f c02 = {-bse * sgn, -bse * sgn};

        v2f o01, o23;
        PK_FMA(o01, i01, c12, c02);
        PK_FMA(o23, i23, c12, c02);
        float4 O = {o01.x, o01.y, o23.x, o23.y};
        ((float4*)out)[(size_t)(base + i) * 256 + (size_t)t] = O;

        // prefetch params for image i+2 (uniform scalar loads, hidden here)
        float4 m0, m1q, m2, m3, m4;
        bool more2 = (i + 2 < IPB);
        if (more2) {
            const float4* M =
                (const float4*)(g_par + (size_t)(base + i + 2) * PSTRIDE);
            m0 = M[0]; m1q = M[1]; m2 = M[2]; m3 = M[3]; m4 = M[4];
        }
        __syncthreads();                              // barrier B
        if (more) {
            c0 = n0; c1 = n1; c2 = n2; c3 = n3; c4 = n4;
            NRc = NRn; NUc = NUn;
            if (more2) { n0 = m0; n1 = m1q; n2 = m2; n3 = m3; n4 = m4; }
            cur ^= 1;
        }
    }
}

extern "C" void kernel_launch(void* const* d_in, const int* in_sizes, int n_in,
                              void* d_out, int out_size, void* d_ws, size_t ws_size,
                              hipStream_t stream) {
    const float* W  = (const float*)d_in[0];
    const float* nr = (const float*)d_in[1];
    const float* nu = (const float*)d_in[2];
    float* out = (float*)d_out;

    init_params_kernel<<<NB / 256, 256, 0, stream>>>(W);
    decode_kernel<<<NBLK, 256, 0, stream>>>(nr, nu, out);
}

// Round 18
// 147.209 us; speedup vs baseline: 1.1495x; 1.0889x over previous
//
#include <hip/hip_runtime.h>
#include <math.h>

#define NB 65536
#define IMGD 32
#define NPIX 1024
#define PSTRIDE 20

typedef float v2f __attribute__((ext_vector_type(2)));

// Packed FP32 (VOP3P, full-rate on CDNA3/4). Compiler never forms these from
// scalar f32 -> emit directly. 64-bit "v" operands = aligned VGPR pairs.
#define PK_FMA(d, a, b, c) \
    asm("v_pk_fma_f32 %0, %1, %2, %3" : "=v"(d) : "v"(a), "v"(b), "v"(c))
#define PK_FMA_CLAMP(d, a, b, c) \
    asm("v_pk_fma_f32 %0, %1, %2, %3 clamp" : "=v"(d) : "v"(a), "v"(b), "v"(c))
#define PK_FMA_ACC(acc, a, b) \
    asm("v_pk_fma_f32 %0, %1, %2, %0" : "+v"(acc) : "v"(a), "v"(b))
#define PK_ADD(d, a, b) \
    asm("v_pk_add_f32 %0, %1, %2" : "=v"(d) : "v"(a), "v"(b))
#define PK_ADD_ACC(acc, a) \
    asm("v_pk_add_f32 %0, %0, %1" : "+v"(acc) : "v"(a))
#define PK_MUL(d, a, b) \
    asm("v_pk_mul_f32 %0, %1, %2" : "=v"(d) : "v"(a), "v"(b))

// Constant tables (same for every image) and per-image derived params.
__device__ __align__(16) float g_r[NPIX];
__device__ __align__(16) float g_th[NPIX];   // theta * 5/(2*pi)
__device__ __align__(16) float g_par[(size_t)NB * PSTRIDE];

__global__ void init_params_kernel(const float* __restrict__ W) {
    int b = blockIdx.x * blockDim.x + threadIdx.x;

    // block 0 additionally fills the constant pixel tables (4 px/thread)
    if (blockIdx.x == 0) {
        int t = threadIdx.x;
        for (int k = 0; k < 4; ++k) {
            int p = t * 4 + k;
            int x = p >> 5, y = p & 31;
            float dx = (float)(x - 16), dy = (float)(y - 16);
            g_r[p] = sqrtf(dx * dx + dy * dy);            // exact -> bitwise
            g_th[p] = atan2f(dy, dx) * 0.79577471545947668f;
        }
    }
    if (b >= NB) return;
    const float* w = W + (size_t)b * 16;
    float* P = g_par + (size_t)b * PSTRIDE;

    float w0 = w[0], w1 = w[1], w2 = w[2], w3 = w[3], w4 = w[4], w5 = w[5],
          w6 = w[6], w7 = w[7], w8 = w[8], w9 = w[9], w10 = w[10], w11 = w[11],
          w12 = w[12], w13 = w[13], w14 = w[14], w15 = w[15];

    P[0] = w0 * 5.0f;                                   // a0
    // layer 1: half = floor(clip(|w1|*8, 2, 12)); |w1|*8 exact (pow2 mul)
    float half = floorf(fminf(fmaxf(fabsf(w1) * 8.0f, 2.0f), 12.0f));
    P[1] = 16.0f - half;                                // lo (exact)
    P[2] = 16.0f + half;                                // hi (exact)
    P[3] = w2 * 0.15625f;                               // s2 (10/64 rev)
    P[4] = w3 * 0.15625f;                               // s3
    P[5] = w4 * 0.0390625f;                             // s4 (5/128 rev)
    P[6] = w5 * 0.15625f;                               // s5o
    P[7] = w6;                                          // bias
    // layer 7 blob center: trunc(16 + w7*5), mul/add un-fused to match ref
    float t7 = __fadd_rn(16.0f, __fmul_rn(w7, 5.0f));
    P[8] = truncf(t7);                                  // bxy
    float sg = 4.0f + fabsf(w7) * 4.0f;
    P[9] = -1.0f / (2.0f * sg * sg);                    // nk
    P[10] = w8 * 10.0f;                                 // t8 (single mul)
    // layer 9: cb = floor(clip(|w9|*8 + 2, 2, 16)); exact chain
    float cb = floorf(fminf(fmaxf(__fadd_rn(fabsf(w9) * 8.0f, 2.0f), 2.0f), 16.0f));
    P[11] = cb;
    P[12] = 1.0f / cb;
    // layer 10: angle = w10 * f32(pi) rounded once; cos/sin of that exact f32
    // in DOUBLE then rounded -> correctly-rounded f32 (matches numpy; OCML's
    // 1-2ulp f32 trig flipped |rot|<3 on border px -> round-1's 0.10 absmax).
    float ang = __fmul_rn(w10, 3.14159265358979323846f);
    P[13] = (float)cos((double)ang);                    // ca
    P[14] = (float)sin((double)ang);                    // sa
    P[15] = w11;
    P[16] = w12 * 0.1f;                                 // k12
    P[17] = w13 * 0.05f;                                // k13
    P[18] = 1.0f + w14;                                 // con
    P[19] = w15;
}

// sin(2*pi*rev): v_fract_f32 + v_sin_f32
__device__ __forceinline__ float hsin(float rev) {
    return __builtin_amdgcn_sinf(__builtin_amdgcn_fractf(rev));
}

// Exact floor(x/cb) for integer-valued x in [0,32), cb in [2,16].
__device__ __forceinline__ float fdivq(float xf, float cb, float rcb) {
    float q = floorf(xf * rcb);
    q += ((q + 1.0f) * cb <= xf) ? 1.0f : 0.0f;
    q -= ((q * cb) > xf) ? 1.0f : 0.0f;
    return q;
}

// Wave64 min/max reduction on the VALU pipe via DPP (row_shr 1/2/4/8 +
// row_bcast:15/31, then readlane 63). dpp_ctrl must be an ICE -> template.
template <int CTRL>
__device__ __forceinline__ float dpp_step_min(float v) {
    int i = __float_as_int(v);
    int s = __builtin_amdgcn_update_dpp(i, i, CTRL, 0xf, 0xf, false);
    return fminf(v, __int_as_float(s));
}
template <int CTRL>
__device__ __forceinline__ float dpp_step_max(float v) {
    int i = __float_as_int(v);
    int s = __builtin_amdgcn_update_dpp(i, i, CTRL, 0xf, 0xf, false);
    return fmaxf(v, __int_as_float(s));
}

// One block = one image. Thread t: x = t>>3 FIXED, y = 4(t&7)..+3.
// FINAL: the session-record kernel (round 11, 145.9 us PASS), resubmitted
// verbatim. Eight structural variants (scalar, pk-layouts, barrier-free,
// wave-per-image, 8-image pipeline, 128-thr blocks, inline-r) were tried;
// all regressed or failed. dur ~= VALU_issue + exposed_mem ~= 146 us is the
// practical floor for this access mix at source level.
__global__ __launch_bounds__(256) void decode_kernel(
        const float* __restrict__ nrand,   // noise_randn
        const float* __restrict__ nunif,   // noise_rand
        float* __restrict__ out) {
    int b = blockIdx.x;
    int t = threadIdx.x;

    const float4* Pq = (const float4*)(g_par + (size_t)b * PSTRIDE);
    float4 q0 = Pq[0], q1 = Pq[1], q2 = Pq[2], q3 = Pq[3], q4 = Pq[4];
    float a0 = q0.x, lo = q0.y, hi = q0.z, s2 = q0.w;
    float s3 = q1.x, s4 = q1.y, s5o = q1.z, w6 = q1.w;
    float bxy = q2.x, nk = q2.y, t8 = q2.z, cb = q2.w;
    float rcb = q3.x, ca = q3.y, sa = q3.z, w11 = q3.w;
    float k12 = q4.x, k13 = q4.y, con = q4.z, w15 = q4.w;

    __shared__ float4 xt4[32];     // {xsum=0.5sin2+0.3px, xm(0/1), -0.6px, gx}
    __shared__ float  rx[32];      // ca*(x-16) un-fused
    __shared__ float  ysum[32];    // 0.5sin3+0.5warp+0.3py+w6-0.5k13
    __shared__ float  ym05[32];    // square y mask (0/0.5)
    __shared__ float  pyt[32];     // checker y parity (0/1)
    __shared__ float  gyt[32];     // exp(nk*dy^2)
    __shared__ float  syt[32];     // sa*(y-16) un-fused
    __shared__ float  stab[63];    // 0.5*sin4(x+y)

    if (t < 32) {
        float xf = (float)t;
        float qx = fdivq(xf, cb, rcb);
        float px = qx - 2.0f * floorf(qx * 0.5f);       // parity 0/1, exact
        float d  = xf - bxy;
        float4 e;
        e.x = 0.5f * hsin(s2 * xf) + 0.3f * px;
        e.y = (xf >= lo && xf < hi) ? 1.0f : 0.0f;
        e.z = -0.6f * px;
        e.w = __expf(d * d * nk);
        xt4[t] = e;
        rx[t] = __fmul_rn(ca, xf - 16.0f);
    } else if (t < 64) {
        int   y  = t - 32;
        float yf = (float)y;
        float qy = fdivq(yf, cb, rcb);
        float py = qy - 2.0f * floorf(qy * 0.5f);
        float d  = yf - bxy;
        ysum[y] = 0.5f * hsin(s3 * yf) + 0.5f * hsin(0.015625f * yf + s5o)
                  + 0.3f * py + w6 - 0.5f * k13;
        ym05[y] = (yf >= lo && yf < hi) ? 0.5f : 0.0f;
        pyt[y]  = py;
        gyt[y]  = __expf(d * d * nk);
        syt[y]  = __fmul_rn(sa, yf - 16.0f);
    } else if (t < 127) {
        int s = t - 64;
        stab[s] = 0.5f * hsin(s4 * (float)s);
    }
    __syncthreads();

    int x  = t >> 3;
    int y0 = (t & 7) * 4;

    float4 X   = xt4[x];
    float  rxv = rx[x];

    // y-pair tables: aligned ds_read_b64, same-addr broadcast across lanes
    v2f ysA = *(const v2f*)&ysum[y0], ysB = *(const v2f*)&ysum[y0 + 2];
    v2f ymA = *(const v2f*)&ym05[y0], ymB = *(const v2f*)&ym05[y0 + 2];
    v2f pyA = *(const v2f*)&pyt[y0],  pyB = *(const v2f*)&pyt[y0 + 2];
    v2f gyA = *(const v2f*)&gyt[y0],  gyB = *(const v2f*)&gyt[y0 + 2];
    v2f syA = *(const v2f*)&syt[y0],  syB = *(const v2f*)&syt[y0 + 2];
    int s0 = x + y0;
    v2f stA = {stab[s0], stab[s0 + 1]}, stB = {stab[s0 + 2], stab[s0 + 3]};

    size_t q = (size_t)b * 256 + (size_t)t;    // float4 index
    float4 R  = ((const float4*)g_r)[t];
    float4 TH = ((const float4*)g_th)[t];
    float4 NR = ((const float4*)nrand)[q];
    float4 NU = ((const float4*)nunif)[q];

    const v2f m1   = {-1.0f, -1.0f};
    const v2f a02  = {a0, a0};
    const v2f xs2  = {X.x, X.x};
    const v2f xm2  = {X.y, X.y};
    const v2f px2  = {X.z, X.z};
    const v2f gx2  = {X.w, X.w};
    const v2f rx2  = {rxv, rxv};
    const v2f nt82 = {-t8, -t8};
    const v2f w112 = {w11, w11};
    const v2f h2   = {0.5f, 0.5f};
    const v2f k122 = {k12, k12};
    const v2f k132 = {k13, k13};

    v2f i01, i23;
    float mn, mx;

#pragma unroll
    for (int k = 0; k < 2; ++k) {
        v2f r2  = k ? (v2f){R.z, R.w}   : (v2f){R.x, R.y};
        v2f th2 = k ? (v2f){TH.z, TH.w} : (v2f){TH.x, TH.y};
        v2f nr2 = k ? (v2f){NR.z, NR.w} : (v2f){NR.x, NR.y};
        v2f nu2 = k ? (v2f){NU.z, NU.w} : (v2f){NU.x, NU.y};
        v2f ys = k ? ysB : ysA, ym = k ? ymB : ymA, py = k ? pyB : pyA;
        v2f gy = k ? gyB : gyA, sy = k ? syB : syA, st = k ? stB : stA;

        v2f v;
        PK_FMA_CLAMP(v, r2, m1, a02);   // layer 0: clip(a0 - r, 0, 1)
        PK_ADD_ACC(v, ys);              // sin3+warp+0.3py+bias-0.5k13
        PK_ADD_ACC(v, xs2);             // sin2+0.3px
        PK_ADD_ACC(v, st);              // diagonal sinusoid
        PK_FMA_ACC(v, xm2, ym);         // layer 1: square (exact masks)
        PK_FMA_ACC(v, px2, py);         // checker cross: -0.6*px*py (exact)
        PK_FMA_ACC(v, gx2, gy);         // gaussian split (<=4e-7)
        v2f dr, dr2, rot, ang;
        PK_ADD(dr, r2, nt82);           // RN(r - t8)  == __fsub_rn
        PK_MUL(dr2, dr, dr);            // RN(dr*dr)   == __fmul_rn
        PK_ADD(rot, sy, rx2);           // RN(ca(x-16) + sa(y-16))
        PK_MUL(ang, th2, w112);
        v2f sn = {hsin(ang.x), hsin(ang.y)};
        PK_FMA_ACC(v, sn, h2);          // angular sinusoid
        PK_FMA_ACC(v, nr2, k122);       // noise_randn
        PK_FMA_ACC(v, nu2, k132);       // noise_rand (-0.5k13 in ysum)

        // discrete mask adds: scalar, bit-exact compare inputs from pk RN ops
        float vx = v.x + ((dr2.x < 10.0f) ? 1.0f : 0.0f);
        float vy = v.y + ((dr2.y < 10.0f) ? 1.0f : 0.0f);
        vx += (fabsf(rot.x) < 3.0f) ? 0.6f : 0.0f;
        vy += (fabsf(rot.y) < 3.0f) ? 0.6f : 0.0f;

        v2f r_ = {vx, vy};
        if (k == 0) { i01 = r_; mn = fminf(vx, vy); mx = fmaxf(vx, vy); }
        else        { i23 = r_; mn = fminf(mn, fminf(vx, vy));
                                mx = fmaxf(mx, fmaxf(vx, vy)); }
    }

    // wave64 reduce on VALU pipe (DPP), result via lane 63
    mn = dpp_step_min<0x111>(mn);   // row_shr:1
    mx = dpp_step_max<0x111>(mx);
    mn = dpp_step_min<0x112>(mn);   // row_shr:2
    mx = dpp_step_max<0x112>(mx);
    mn = dpp_step_min<0x114>(mn);   // row_shr:4
    mx = dpp_step_max<0x114>(mx);
    mn = dpp_step_min<0x118>(mn);   // row_shr:8
    mx = dpp_step_max<0x118>(mx);
    mn = dpp_step_min<0x142>(mn);   // row_bcast:15
    mx = dpp_step_max<0x142>(mx);
    mn = dpp_step_min<0x143>(mn);   // row_bcast:31
    mx = dpp_step_max<0x143>(mx);
    mn = __int_as_float(__builtin_amdgcn_readlane(__float_as_int(mn), 63));
    mx = __int_as_float(__builtin_amdgcn_readlane(__float_as_int(mx), 63));

    __shared__ float smn[4], smx[4];
    int wid = t >> 6;
    if ((t & 63) == 0) { smn[wid] = mn; smx[wid] = mx; }
    __syncthreads();
    mn = fminf(fminf(smn[0], smn[1]), fminf(smn[2], smn[3]));
    mx = fmaxf(fmaxf(smx[0], smx[1]), fmaxf(smx[2], smx[3]));

    // contrast (v-0.5)*con+0.5, optional inversion, min-max normalize:
    // affine => o = v*sgn + c0; flips tracked by signs of con and w15.
    float ac    = fabsf(con);
    float denom = fmaf(ac, mx - mn, 1e-8f);
    float s     = ac / denom;
    bool  eff   = (w15 > 0.0f) != (con < 0.0f);
    float bse   = eff ? mx : mn;
    float sgn   = eff ? -s : s;
    v2f c12 = {sgn, sgn};
    v2f c02 = {-bse * sgn, -bse * sgn};

    v2f o01, o23;
    PK_FMA(o01, i01, c12, c02);
    PK_FMA(o23, i23, c12, c02);
    float4 O = {o01.x, o01.y, o23.x, o23.y};
    ((float4*)out)[q] = O;
}

extern "C" void kernel_launch(void* const* d_in, const int* in_sizes, int n_in,
                              void* d_out, int out_size, void* d_ws, size_t ws_size,
                              hipStream_t stream) {
    const float* W  = (const float*)d_in[0];
    const float* nr = (const float*)d_in[1];
    const float* nu = (const float*)d_in[2];
    float* out = (float*)d_out;

    init_params_kernel<<<NB / 256, 256, 0, stream>>>(W);
    decode_kernel<<<NB, 256, 0, stream>>>(nr, nu, out);
}